// Round 2
// baseline (673.235 us; speedup 1.0000x reference)
//
#include <hip/hip_runtime.h>

#define TSTEPS 336
#define NI 24
#define NH 128
#define NG 384
#define RW 16          // batch rows per workgroup
#define NTHREADS 512
#define NWG 256        // 4096 / RW

typedef __attribute__((ext_vector_type(8))) short bf16x8;  // 8 bf16 in 4 VGPRs (guide-verified operand type)
typedef __attribute__((ext_vector_type(4))) float f32x4;
typedef unsigned short u16;
typedef unsigned int u32;

// ---- LDS layout: all MFMA fragments are [tile][kt][lane][8] so reads are lane*16B contiguous ----
struct __align__(16) Smem {
    u16 whhf[24][4][64][8];           // 98304 B  Whh B-frags (bf16)
    u16 wihf[24 * 384 + 128];         // 18688 B  Wih B-frags, tiles packed at 768B (lanes 0..47) + pad
    u16 w1f[2][4][64][8];             // 8192  W1 B-frags
    u16 w2f[2][64][8];                // 2048  W2 B-frags (K=24, zero-padded)
    u16 h2of[4][64][8];               // 4096  h2o as B-frag, col 0 only
    u16 hhi[4][64][8];                // 4096  hidden hi (A-frag layout)
    u16 hlo[4][64][8];                // 4096  hidden lo
    u16 chi[64][8], clo[64][8];       // 2048  c hi/lo A-frags (K=24, lanes>=48 zero)
    u16 x1hi[64][8], x1lo[64][8];     // 2048
    u16 x2hi[64][8], x2lo[64][8];     // 2048
    float xt[2][16][52];              // 6656  x(t) staging, padded rows (52 floats)
    float a1[16][24], a2[16][24];     // 3072
    float exw1h[16][24], exs1[16][24], exs2[16][24]; // 4608
};                                    // total 160000 B <= 163840

__device__ __forceinline__ u16 f2bf(float f) {
    u32 u = __float_as_uint(f);
    return (u16)((u + 0x7FFFu + ((u >> 16) & 1u)) >> 16);
}
__device__ __forceinline__ float bf2f(u16 h) { return __uint_as_float(((u32)h) << 16); }
__device__ __forceinline__ float frcp(float x) { return __builtin_amdgcn_rcpf(x); }
__device__ __forceinline__ float fex2(float x) { return __builtin_amdgcn_exp2f(x); }
__device__ __forceinline__ float sigm(float x) { return frcp(1.0f + fex2(-1.4426950408889634f * x)); }
__device__ __forceinline__ float tanhf_(float x) { return 1.0f - 2.0f * frcp(1.0f + fex2(2.8853900817779268f * x)); }
__device__ __forceinline__ float fexp(float x) { return fex2(1.4426950408889634f * x); }

// raw barrier: fence LDS only; keeps global (vmcnt) loads in flight across it
__device__ __forceinline__ void bar() {
    asm volatile("s_waitcnt lgkmcnt(0)" ::: "memory");
    __builtin_amdgcn_s_barrier();
    asm volatile("" ::: "memory");
}

#define MFMA(A, B, C) __builtin_amdgcn_mfma_f32_16x16x32_bf16((A), (B), (C), 0, 0, 0)

__global__ __launch_bounds__(NTHREADS, 2) void gru_persist(
    const float* __restrict__ x, const float* __restrict__ wih, const float* __restrict__ whh,
    const float* __restrict__ bih, const float* __restrict__ bhh,
    const float* __restrict__ h2ow, const float* __restrict__ h2ob_p,
    const float* __restrict__ w1w, const float* __restrict__ w1b_p,
    const float* __restrict__ w2w, const float* __restrict__ w2b_p,
    float* __restrict__ out)
{
    extern __shared__ char smem_raw[];
    Smem& S = *reinterpret_cast<Smem*>(smem_raw);
    const int tid = threadIdx.x;
    const int l = tid & 63;
    const int w = tid >> 6;      // wave 0..7
    const int g = l >> 4;        // lane group
    const int cl = l & 15;
    const int b0 = blockIdx.x * RW;

    // ---- prologue: zero LDS, pack weight fragments ----
    for (int i = tid; i < (int)(sizeof(Smem) / 4); i += NTHREADS) ((u32*)&S)[i] = 0u;
    bar();

    for (int idx = tid; idx < NG * NH; idx += NTHREADS) {          // Whh [384][128]
        int c = idx >> 7, k = idx & 127;
        S.whhf[c >> 4][k >> 5][(c & 15) + ((k >> 3) & 3) * 16][k & 7] = f2bf(whh[idx]);
    }
    for (int idx = tid; idx < NG * NI; idx += NTHREADS) {          // Wih [384][24]
        int c = idx / NI, k = idx - c * NI;
        int lane = (c & 15) + (k >> 3) * 16;
        S.wihf[(c >> 4) * 384 + lane * 8 + (k & 7)] = f2bf(wih[idx]);
    }
    for (int idx = tid; idx < NI * NH; idx += NTHREADS) {          // W1 [24][128]
        int c = idx >> 7, k = idx & 127;
        S.w1f[c >> 4][k >> 5][(c & 15) + ((k >> 3) & 3) * 16][k & 7] = f2bf(w1w[idx]);
    }
    for (int idx = tid; idx < NI * NI; idx += NTHREADS) {          // W2 [24][24]
        int c = idx / NI, k = idx - c * NI;
        S.w2f[c >> 4][(c & 15) + (k >> 3) * 16][k & 7] = f2bf(w2w[idx]);
    }
    for (int k = tid; k < NH; k += NTHREADS)                       // h2o_W col 0
        S.h2of[k >> 5][((k >> 3) & 3) * 16][k & 7] = f2bf(h2ow[k]);
    if (tid < 384) S.a1[tid & 15][tid >> 4] = 1.0f;                // a1=1, a2=0 (zeroed)

    // per-lane constants
    const float bR  = bih[w * 16 + cl] + bhh[w * 16 + cl];
    const float bZ  = bih[128 + w * 16 + cl] + bhh[128 + w * 16 + cl];
    const float bxN = bih[256 + w * 16 + cl];
    const float bhN = bhh[256 + w * 16 + cl];
    const float w1bias = (w == 0) ? w1b_p[cl] : ((w == 1 && cl < 8) ? w1b_p[16 + cl] : 0.0f);
    const float w2b0 = w2b_p[cl];
    const float w2b1 = (cl < 8) ? w2b_p[16 + cl] : 0.0f;
    const float h2ob = h2ob_p[0];

    // where this lane's hidden unit lives in the h A-frag arrays
    const int unit = w * 16 + cl;               // 0..127
    const int ktH = unit >> 5;
    const int lpB = 4 * g + 16 * ((unit >> 3) & 3);
    const int eH = unit & 7;

    // x(t=0) staging
    if (tid < 192) {
        const float* src = x + ((size_t)(b0 + tid / 12) * TSTEPS) * 48 + (tid % 12) * 4;
        *(float4*)&S.xt[0][tid / 12][(tid % 12) * 4] = *(const float4*)src;
    }
    __syncthreads();

    for (int t = 0; t < TSTEPS; ++t) {
        const int cur = t & 1, nxt = cur ^ 1;
        float4 xf;
        const bool ld = (tid < 192) && (t + 1 < TSTEPS);
        if (ld) {   // prefetch x(t+1) into regs; stays in flight across raw barriers
            const float* src = x + ((size_t)(b0 + tid / 12) * TSTEPS + (t + 1)) * 48 + (tid % 12) * 4;
            xf = *(const float4*)src;
        }
        // ---- S0: c = a1*h1 + a2*h2 ; build c/x A-frags (hi+lo split) ----
        if (tid < 384) {
            int rr = tid & 15, j = tid >> 4;
            float h1 = S.xt[cur][rr][j];
            float h2 = S.xt[cur][rr][24 + j];
            float cv = S.a1[rr][j] * h1 + S.a2[rr][j] * h2;
            int lane = rr + (j >> 3) * 16, e = j & 7;
            u16 hi = f2bf(cv);
            S.chi[lane][e] = hi;  S.clo[lane][e] = f2bf(cv - bf2f(hi));
            hi = f2bf(h1);
            S.x1hi[lane][e] = hi; S.x1lo[lane][e] = f2bf(h1 - bf2f(hi));
            hi = f2bf(h2);
            S.x2hi[lane][e] = hi; S.x2lo[lane][e] = f2bf(h2 - bf2f(hi));
        }
        bar(); // B1
        // ---- S1a: gate matmuls. wave w owns col-tiles w (r), w+8 (z), w+16 (n) => same 16 units ----
        f32x4 accR = {bR, bR, bR, bR};
        f32x4 accZ = {bZ, bZ, bZ, bZ};
        f32x4 accGX = {bxN, bxN, bxN, bxN};
        f32x4 accGH = {0.f, 0.f, 0.f, 0.f};
        {
            bf16x8 cH = *(const bf16x8*)&S.chi[l][0];
            bf16x8 cL = *(const bf16x8*)&S.clo[l][0];
            bf16x8 wr = *(const bf16x8*)&S.wihf[w * 384 + l * 8];
            bf16x8 wz = *(const bf16x8*)&S.wihf[(w + 8) * 384 + l * 8];
            bf16x8 wn = *(const bf16x8*)&S.wihf[(w + 16) * 384 + l * 8];
            accR = MFMA(cH, wr, accR);  accR = MFMA(cL, wr, accR);
            accZ = MFMA(cH, wz, accZ);  accZ = MFMA(cL, wz, accZ);
            accGX = MFMA(cH, wn, accGX); accGX = MFMA(cL, wn, accGX);
#pragma unroll
            for (int kt = 0; kt < 4; ++kt) {
                bf16x8 hH = *(const bf16x8*)&S.hhi[kt][l][0];
                bf16x8 hL = *(const bf16x8*)&S.hlo[kt][l][0];
                bf16x8 wR = *(const bf16x8*)&S.whhf[w][kt][l][0];
                bf16x8 wZ = *(const bf16x8*)&S.whhf[w + 8][kt][l][0];
                bf16x8 wN = *(const bf16x8*)&S.whhf[w + 16][kt][l][0];
                accR = MFMA(hH, wR, accR);   accR = MFMA(hL, wR, accR);
                accZ = MFMA(hH, wZ, accZ);   accZ = MFMA(hL, wZ, accZ);
                accGH = MFMA(hH, wN, accGH); accGH = MFMA(hL, wN, accGH);
            }
        }
        // gates fully in-register; D layout: row = 4g+i, col = cl
        u16 hnhi[4], hnlo[4];
#pragma unroll
        for (int i = 0; i < 4; ++i) {
            float r = sigm(accR[i]);
            float z = sigm(accZ[i]);
            float n = tanhf_(accGX[i] + r * (accGH[i] + bhN));
            float hold = bf2f(S.hhi[ktH][lpB + i][eH]) + bf2f(S.hlo[ktH][lpB + i][eH]);
            float hv = (1.0f - z) * n + z * hold;
            u16 hi = f2bf(hv);
            hnhi[i] = hi;
            hnlo[i] = f2bf(hv - bf2f(hi));
        }
        bar(); // B2: all frag reads done
#pragma unroll
        for (int i = 0; i < 4; ++i) {
            S.hhi[ktH][lpB + i][eH] = hnhi[i];
            S.hlo[ktH][lpB + i][eH] = hnlo[i];
        }
        bar(); // B3: new h visible
        // ---- S2a: head matmuls off new h ----
        if (w < 2) {            // w1h tile w
            f32x4 acc = {w1bias, w1bias, w1bias, w1bias};
#pragma unroll
            for (int kt = 0; kt < 4; ++kt) {
                bf16x8 hH = *(const bf16x8*)&S.hhi[kt][l][0];
                bf16x8 hL = *(const bf16x8*)&S.hlo[kt][l][0];
                bf16x8 wf = *(const bf16x8*)&S.w1f[w][kt][l][0];
                acc = MFMA(hH, wf, acc); acc = MFMA(hL, wf, acc);
            }
            int col = w * 16 + cl;
            if (col < 24) {
#pragma unroll
                for (int i = 0; i < 4; ++i) S.exw1h[4 * g + i][col] = acc[i];
            }
        } else if (w < 4) {     // s1 (w==2) / s2 (w==3)
            const u16(*xh)[8] = (w == 2) ? S.x1hi : S.x2hi;
            const u16(*xl)[8] = (w == 2) ? S.x1lo : S.x2lo;
            bf16x8 aH = *(const bf16x8*)&xh[l][0];
            bf16x8 aL = *(const bf16x8*)&xl[l][0];
            bf16x8 w20 = *(const bf16x8*)&S.w2f[0][l][0];
            bf16x8 w21 = *(const bf16x8*)&S.w2f[1][l][0];
            f32x4 acc0 = {w2b0, w2b0, w2b0, w2b0};
            f32x4 acc1 = {w2b1, w2b1, w2b1, w2b1};
            acc0 = MFMA(aH, w20, acc0); acc0 = MFMA(aL, w20, acc0);
            acc1 = MFMA(aH, w21, acc1); acc1 = MFMA(aL, w21, acc1);
            float(*ex)[24] = (w == 2) ? S.exs1 : S.exs2;
#pragma unroll
            for (int i = 0; i < 4; ++i) ex[4 * g + i][cl] = acc0[i];
            if (cl < 8) {
#pragma unroll
                for (int i = 0; i < 4; ++i) ex[4 * g + i][16 + cl] = acc1[i];
            }
        } else if (w == 4) {    // out = tanh(h @ h2o + b)
            f32x4 acc = {0.f, 0.f, 0.f, 0.f};
#pragma unroll
            for (int kt = 0; kt < 4; ++kt) {
                bf16x8 hH = *(const bf16x8*)&S.hhi[kt][l][0];
                bf16x8 hL = *(const bf16x8*)&S.hlo[kt][l][0];
                bf16x8 of = *(const bf16x8*)&S.h2of[kt][l][0];
                acc = MFMA(hH, of, acc); acc = MFMA(hL, of, acc);
            }
            if (cl == 0) {
#pragma unroll
                for (int i = 0; i < 4; ++i)
                    out[(size_t)(b0 + 4 * g + i) * TSTEPS + t] = tanhf_(acc[i] + h2ob);
            }
        }
        bar(); // B4
        // ---- S2b: attention weights a1,a2 ----
        if (tid < 384) {
            int rr = tid & 15, j = tid >> 4;
            float v = S.exw1h[rr][j];
            float e1 = fexp(tanhf_(v + S.exs1[rr][j]));
            float e2 = fexp(tanhf_(v + S.exs2[rr][j]));
            float inv = frcp(e1 + e2);
            S.a1[rr][j] = e1 * inv;
            S.a2[rr][j] = e2 * inv;
        }
        if (ld) *(float4*)&S.xt[nxt][tid / 12][(tid % 12) * 4] = xf;
        __syncthreads(); // B5: full drain (x prefetch + a-writes visible)
    }
}

extern "C" void kernel_launch(void* const* d_in, const int* in_sizes, int n_in,
                              void* d_out, int out_size, void* d_ws, size_t ws_size,
                              hipStream_t stream) {
    const float* x    = (const float*)d_in[0];
    const float* wih  = (const float*)d_in[1];
    const float* whh  = (const float*)d_in[2];
    const float* bih  = (const float*)d_in[3];
    const float* bhh  = (const float*)d_in[4];
    const float* h2ow = (const float*)d_in[5];
    const float* h2ob = (const float*)d_in[6];
    const float* w1w  = (const float*)d_in[7];
    const float* w1b  = (const float*)d_in[8];
    const float* w2w  = (const float*)d_in[9];
    const float* w2b  = (const float*)d_in[10];
    float* out = (float*)d_out;

    const size_t smem = sizeof(Smem);
    hipFuncSetAttribute((const void*)gru_persist,
                        hipFuncAttributeMaxDynamicSharedMemorySize, (int)smem);
    gru_persist<<<NWG, NTHREADS, smem, stream>>>(x, wih, whh, bih, bhh,
                                                 h2ow, h2ob, w1w, w1b, w2w, w2b, out);
}

// Round 3
// 561.804 us; speedup vs baseline: 1.1983x; 1.1983x over previous
//
#include <hip/hip_runtime.h>

#define TSTEPS 336
#define NI 24
#define NH 128
#define RW 16          // batch rows per workgroup
#define NTHREADS 512
#define NWG 256        // 4096 / RW

typedef __attribute__((ext_vector_type(8))) short bf16x8;
typedef __attribute__((ext_vector_type(4))) float f32x4;
typedef unsigned short u16;
typedef unsigned int u32;

struct __align__(16) Smem {
    // ---- weight staging: written once in prologue, read once into registers ----
    u16 whhf[24][4][64][8];           // 98304 B
    u16 wihf[24 * 384 + 128];         // 18688 B
    u16 w1f[2][4][64][8];             // 8192
    u16 w2f[2][64][8];                // 2048
    u16 h2of[4][64][8];               // 4096
    // ---- loop-live ----
    u16 hhi[4][80][8];                // 5120  h hi frags, slot-swizzled (p + p/4)
    u16 hlo[4][80][8];                // 5120
    u16 chi[64][8], clo[64][8];       // 2048
    u16 x1hi[64][8], x1lo[64][8];     // 2048
    u16 x2hi[64][8], x2lo[64][8];     // 2048
    float xt[2][16][52];              // 6656  x staging, padded rows
    float exw1h[16][26], exs1[16][26], exs2[16][26]; // 4992, stride-26 pad
};                                    // 159360 B <= 163840

__device__ __forceinline__ u16 f2bf(float f) {
    u32 u = __float_as_uint(f);
    return (u16)((u + 0x7FFFu + ((u >> 16) & 1u)) >> 16);
}
__device__ __forceinline__ float bf2f(u16 h) { return __uint_as_float(((u32)h) << 16); }
__device__ __forceinline__ float frcp(float x) { return __builtin_amdgcn_rcpf(x); }
__device__ __forceinline__ float fex2(float x) { return __builtin_amdgcn_exp2f(x); }
__device__ __forceinline__ float sigm(float x) { return frcp(1.0f + fex2(-1.4426950408889634f * x)); }
__device__ __forceinline__ float tanhf_(float x) { return 1.0f - 2.0f * frcp(1.0f + fex2(2.8853900817779268f * x)); }
__device__ __forceinline__ float fexp(float x) { return fex2(1.4426950408889634f * x); }

// LDS-only barrier: global prefetch stays in flight
__device__ __forceinline__ void bar() {
    asm volatile("s_waitcnt lgkmcnt(0)" ::: "memory");
    __builtin_amdgcn_s_barrier();
    asm volatile("" ::: "memory");
}

#define MFMA(A, B, C) __builtin_amdgcn_mfma_f32_16x16x32_bf16((A), (B), (C), 0, 0, 0)

__global__ __launch_bounds__(NTHREADS, 2) void gru_persist(
    const float* __restrict__ x, const float* __restrict__ wih, const float* __restrict__ whh,
    const float* __restrict__ bih, const float* __restrict__ bhh,
    const float* __restrict__ h2ow, const float* __restrict__ h2ob_p,
    const float* __restrict__ w1w, const float* __restrict__ w1b_p,
    const float* __restrict__ w2w, const float* __restrict__ w2b_p,
    float* __restrict__ out)
{
    extern __shared__ char smem_raw[];
    Smem& S = *reinterpret_cast<Smem*>(smem_raw);
    const int tid = threadIdx.x;
    const int l = tid & 63;
    const int w = tid >> 6;
    const int g = l >> 4;
    const int cl = l & 15;
    const int b0 = blockIdx.x * RW;

    // ---- prologue: zero LDS ----
    for (int i = tid; i < (int)(sizeof(Smem) / 4); i += NTHREADS) ((u32*)&S)[i] = 0u;
    bar();
    // pack weight fragments into LDS staging
    for (int idx = tid; idx < 384 * NH; idx += NTHREADS) {          // Whh [384][128]
        int c = idx >> 7, k = idx & 127;
        S.whhf[c >> 4][k >> 5][(c & 15) + ((k >> 3) & 3) * 16][k & 7] = f2bf(whh[idx]);
    }
    for (int idx = tid; idx < 384 * NI; idx += NTHREADS) {          // Wih [384][24]
        int c = idx / NI, k = idx - c * NI;
        int lane = (c & 15) + (k >> 3) * 16;
        S.wihf[(c >> 4) * 384 + lane * 8 + (k & 7)] = f2bf(wih[idx]);
    }
    for (int idx = tid; idx < NI * NH; idx += NTHREADS) {           // W1 [24][128]
        int c = idx >> 7, k = idx & 127;
        S.w1f[c >> 4][k >> 5][(c & 15) + ((k >> 3) & 3) * 16][k & 7] = f2bf(w1w[idx]);
    }
    for (int idx = tid; idx < NI * NI; idx += NTHREADS) {           // W2 [24][24]
        int c = idx / NI, k = idx - c * NI;
        S.w2f[c >> 4][(c & 15) + (k >> 3) * 16][k & 7] = f2bf(w2w[idx]);
    }
    for (int k = tid; k < NH; k += NTHREADS)                        // h2o col 0
        S.h2of[k >> 5][((k >> 3) & 3) * 16][k & 7] = f2bf(h2ow[k]);
    // x(t=0) staging
    if (tid < 192) {
        const float* src = x + ((size_t)(b0 + tid / 12) * TSTEPS) * 48 + (tid % 12) * 4;
        *(float4*)&S.xt[0][tid / 12][(tid % 12) * 4] = *(const float4*)src;
    }
    bar();

    // ---- weights -> persistent registers (per-wave tiles w, w+8, w+16) ----
    bf16x8 wihR[3], whhR[3][4], w1R[4], w2R[2], h2oR[4];
#pragma unroll
    for (int s = 0; s < 3; ++s) {
        int tw = w + 8 * s;
        wihR[s] = *(const bf16x8*)&S.wihf[tw * 384 + l * 8];
#pragma unroll
        for (int kt = 0; kt < 4; ++kt) whhR[s][kt] = *(const bf16x8*)&S.whhf[tw][kt][l][0];
    }
#pragma unroll
    for (int kt = 0; kt < 4; ++kt) {
        w1R[kt] = *(const bf16x8*)&S.w1f[w & 1][kt][l][0];
        h2oR[kt] = *(const bf16x8*)&S.h2of[kt][l][0];
    }
    w2R[0] = *(const bf16x8*)&S.w2f[0][l][0];
    w2R[1] = *(const bf16x8*)&S.w2f[1][l][0];

    // per-lane constants
    const float bR  = bih[w * 16 + cl] + bhh[w * 16 + cl];
    const float bZ  = bih[128 + w * 16 + cl] + bhh[128 + w * 16 + cl];
    const float bxN = bih[256 + w * 16 + cl];
    const float bhN = bhh[256 + w * 16 + cl];
    const float w1bias = (w == 0) ? w1b_p[cl] : ((w == 1 && cl < 8) ? w1b_p[16 + cl] : 0.0f);
    const float w2b0 = w2b_p[cl];
    const float w2b1 = (cl < 8) ? w2b_p[16 + cl] : 0.0f;
    const float h2ob = h2ob_p[0];

    // h ownership: unit = w*16+cl, rows 4g..4g+3
    const int unit = w * 16 + cl;
    const int ktH = w >> 1;                         // unit>>5
    const int cc = (2 * w + (cl >> 3)) & 3;         // (unit>>3)&3
    const int hsB = 5 * g + 20 * cc;                // swizzled slot base: p + p/4
    const int eH = cl & 7;
    const int hsl = l + (l >> 2);                   // swizzled read slot
    float h_reg[4] = {0.f, 0.f, 0.f, 0.f};

    // build c(0)=h1 and x(0) fragments
    if (tid < 384) {
        int rr = tid & 15, j = tid >> 4;
        float h1 = S.xt[0][rr][j];
        float h2 = S.xt[0][rr][24 + j];
        int lane = rr + (j >> 3) * 16, el = j & 7;
        u16 hi = f2bf(h1);
        S.chi[lane][el] = hi;  S.clo[lane][el] = f2bf(h1 - bf2f(hi));
        S.x1hi[lane][el] = hi; S.x1lo[lane][el] = S.clo[lane][el];
        hi = f2bf(h2);
        S.x2hi[lane][el] = hi; S.x2lo[lane][el] = f2bf(h2 - bf2f(hi));
    }
    __syncthreads();

    for (int t = 0; t < TSTEPS; ++t) {
        const int nxt = (t + 1) & 1;
        float4 xf;
        const bool ld = (tid < 192) && (t + 1 < TSTEPS);
        if (ld) {
            const float* src = x + ((size_t)(b0 + tid / 12) * TSTEPS + (t + 1)) * 48 + (tid % 12) * 4;
            xf = *(const float4*)src;
        }
        // ---- phase 1: gate matmuls (reg weights) + x-part of s1/s2 ----
        f32x4 accR = {bR, bR, bR, bR};
        f32x4 accZ = {bZ, bZ, bZ, bZ};
        f32x4 accGX = {bxN, bxN, bxN, bxN};
        f32x4 accGH = {0.f, 0.f, 0.f, 0.f};
        {
            bf16x8 cH = *(const bf16x8*)&S.chi[l][0];
            bf16x8 cL = *(const bf16x8*)&S.clo[l][0];
            accR = MFMA(cH, wihR[0], accR);   accR = MFMA(cL, wihR[0], accR);
            accZ = MFMA(cH, wihR[1], accZ);   accZ = MFMA(cL, wihR[1], accZ);
            accGX = MFMA(cH, wihR[2], accGX); accGX = MFMA(cL, wihR[2], accGX);
#pragma unroll
            for (int kt = 0; kt < 4; ++kt) {
                bf16x8 hH = *(const bf16x8*)&S.hhi[kt][hsl][0];
                bf16x8 hL = *(const bf16x8*)&S.hlo[kt][hsl][0];
                accR = MFMA(hH, whhR[0][kt], accR);   accR = MFMA(hL, whhR[0][kt], accR);
                accZ = MFMA(hH, whhR[1][kt], accZ);   accZ = MFMA(hL, whhR[1][kt], accZ);
                accGH = MFMA(hH, whhR[2][kt], accGH); accGH = MFMA(hL, whhR[2][kt], accGH);
            }
        }
        if (w == 2 || w == 3) {     // s1/s2 x-parts (independent of h_new)
            const u16(*xh)[8] = (w == 2) ? S.x1hi : S.x2hi;
            const u16(*xl)[8] = (w == 2) ? S.x1lo : S.x2lo;
            bf16x8 aH = *(const bf16x8*)&xh[l][0];
            bf16x8 aL = *(const bf16x8*)&xl[l][0];
            f32x4 a0 = {w2b0, w2b0, w2b0, w2b0};
            f32x4 a1v = {w2b1, w2b1, w2b1, w2b1};
            a0 = MFMA(aH, w2R[0], a0);   a0 = MFMA(aL, w2R[0], a0);
            a1v = MFMA(aH, w2R[1], a1v); a1v = MFMA(aL, w2R[1], a1v);
            float(*ex)[26] = (w == 2) ? S.exs1 : S.exs2;
#pragma unroll
            for (int i = 0; i < 4; ++i) ex[4 * g + i][cl] = a0[i];
            if (cl < 8) {
#pragma unroll
                for (int i = 0; i < 4; ++i) ex[4 * g + i][16 + cl] = a1v[i];
            }
        }
        // gates; h_old in registers
        u16 hnhi[4], hnlo[4];
#pragma unroll
        for (int i = 0; i < 4; ++i) {
            float r = sigm(accR[i]);
            float z = sigm(accZ[i]);
            float n = tanhf_(accGX[i] + r * (accGH[i] + bhN));
            float hv = (1.0f - z) * n + z * h_reg[i];
            h_reg[i] = hv;
            u16 hi = f2bf(hv);
            hnhi[i] = hi;
            hnlo[i] = f2bf(hv - bf2f(hi));
        }
        bar(); // B2: phase-1 frag reads done
        // ---- h store (swizzled slots) + x(t+1) staging ----
#pragma unroll
        for (int i = 0; i < 4; ++i) {
            S.hhi[ktH][hsB + i][eH] = hnhi[i];
            S.hlo[ktH][hsB + i][eH] = hnlo[i];
        }
        if (ld) *(float4*)&S.xt[nxt][tid / 12][(tid % 12) * 4] = xf;
        bar(); // B3: new h + x(t+1) visible
        // ---- phase 2: w1h (w0,w1), out (w2), x(t+1) frag build (w3..w7) ----
        if (w < 2) {
            f32x4 acc = {w1bias, w1bias, w1bias, w1bias};
#pragma unroll
            for (int kt = 0; kt < 4; ++kt) {
                bf16x8 hH = *(const bf16x8*)&S.hhi[kt][hsl][0];
                bf16x8 hL = *(const bf16x8*)&S.hlo[kt][hsl][0];
                acc = MFMA(hH, w1R[kt], acc); acc = MFMA(hL, w1R[kt], acc);
            }
            int col = w * 16 + cl;
            if (col < 24) {
#pragma unroll
                for (int i = 0; i < 4; ++i) S.exw1h[4 * g + i][col] = acc[i];
            }
        } else if (w == 2) {
            f32x4 acc = {0.f, 0.f, 0.f, 0.f};
#pragma unroll
            for (int kt = 0; kt < 4; ++kt) {
                bf16x8 hH = *(const bf16x8*)&S.hhi[kt][hsl][0];
                bf16x8 hL = *(const bf16x8*)&S.hlo[kt][hsl][0];
                acc = MFMA(hH, h2oR[kt], acc); acc = MFMA(hL, h2oR[kt], acc);
            }
            if (cl == 0) {
#pragma unroll
                for (int i = 0; i < 4; ++i)
                    out[(size_t)(b0 + 4 * g + i) * TSTEPS + t] = tanhf_(acc[i] + h2ob);
            }
        } else {
            int e = tid - 192;  // 0..319 over waves 3..7
#pragma unroll
            for (int rep = 0; rep < 2; ++rep) {
                int ee = e + rep * 320;
                if (ee < 384) {
                    int rr = ee & 15, j = ee >> 4;
                    float h1 = S.xt[nxt][rr][j];
                    float h2 = S.xt[nxt][rr][24 + j];
                    int lane = rr + (j >> 3) * 16, el = j & 7;
                    u16 hi = f2bf(h1);
                    S.x1hi[lane][el] = hi; S.x1lo[lane][el] = f2bf(h1 - bf2f(hi));
                    hi = f2bf(h2);
                    S.x2hi[lane][el] = hi; S.x2lo[lane][el] = f2bf(h2 - bf2f(hi));
                }
            }
        }
        bar(); // B4: exw1h/x-frags visible
        // ---- phase 3: a1,a2 in-register -> c(t+1) frags ----
        if (tid < 384) {
            int rr = tid & 15, j = tid >> 4;
            float v = S.exw1h[rr][j];
            float e1 = fexp(tanhf_(v + S.exs1[rr][j]));
            float e2 = fexp(tanhf_(v + S.exs2[rr][j]));
            float inv = frcp(e1 + e2);
            float h1 = S.xt[nxt][rr][j];
            float h2 = S.xt[nxt][rr][24 + j];
            float cv = (e1 * inv) * h1 + (e2 * inv) * h2;
            int lane = rr + (j >> 3) * 16, el = j & 7;
            u16 hi = f2bf(cv);
            S.chi[lane][el] = hi;
            S.clo[lane][el] = f2bf(cv - bf2f(hi));
        }
        bar(); // B5: c frags ready for next step
    }
}

extern "C" void kernel_launch(void* const* d_in, const int* in_sizes, int n_in,
                              void* d_out, int out_size, void* d_ws, size_t ws_size,
                              hipStream_t stream) {
    const float* x    = (const float*)d_in[0];
    const float* wih  = (const float*)d_in[1];
    const float* whh  = (const float*)d_in[2];
    const float* bih  = (const float*)d_in[3];
    const float* bhh  = (const float*)d_in[4];
    const float* h2ow = (const float*)d_in[5];
    const float* h2ob = (const float*)d_in[6];
    const float* w1w  = (const float*)d_in[7];
    const float* w1b  = (const float*)d_in[8];
    const float* w2w  = (const float*)d_in[9];
    const float* w2b  = (const float*)d_in[10];
    float* out = (float*)d_out;

    const size_t smem = sizeof(Smem);
    hipFuncSetAttribute((const void*)gru_persist,
                        hipFuncAttributeMaxDynamicSharedMemorySize, (int)smem);
    gru_persist<<<NWG, NTHREADS, smem, stream>>>(x, wih, whh, bih, bhh,
                                                 h2ow, h2ob, w1w, w1b, w2w, w2b, out);
}

// Round 4
// 536.906 us; speedup vs baseline: 1.2539x; 1.0464x over previous
//
#include <hip/hip_runtime.h>

#define TSTEPS 336
#define NI 24
#define NH 128
#define RW 16          // batch rows per workgroup
#define NTHREADS 512
#define NWG 256        // 4096 / RW

typedef __attribute__((ext_vector_type(8))) short bf16x8;
typedef __attribute__((ext_vector_type(4))) float f32x4;
typedef unsigned short u16;
typedef unsigned int u32;

struct __align__(16) Smem {
    // ---- weight staging: written once in prologue, read once into registers ----
    u16 whhf[24][4][64][8];           // 98304 B
    u16 wihf[24 * 384 + 128];         // 18688 B
    u16 w1f[2][4][64][8];             // 8192
    u16 w2f[2][64][8];                // 2048
    u16 h2of[4][64][8];               // 4096
    // ---- loop-live ----
    u16 hhi[4][72][8];                // 4608  h hi frags, slot phi(p)=p+((p>>3)&1)+2*(p>>4)
    u16 hlo[4][72][8];                // 4608
    u16 chi[64][8], clo[64][8];       // 2048  c hi/lo A-frags (K=24, lanes>=48 zero)
    u16 x1hi[64][8], x2hi[64][8];     // 2048  x A-frags, hi only (head path)
    float xt[2][16][52];              // 6656  x staging, padded rows
    float exw1h[16][26], exs1[16][26], exs2[16][26]; // 4992, stride-26 pad
};                                    // 156288 B <= 163840

__device__ __forceinline__ u16 f2bf(float f) {
    u32 u = __float_as_uint(f);
    return (u16)((u + 0x7FFFu + ((u >> 16) & 1u)) >> 16);
}
__device__ __forceinline__ float bf2f(u16 h) { return __uint_as_float(((u32)h) << 16); }
__device__ __forceinline__ float frcp(float x) { return __builtin_amdgcn_rcpf(x); }
__device__ __forceinline__ float fex2(float x) { return __builtin_amdgcn_exp2f(x); }
__device__ __forceinline__ float sigm(float x) { return frcp(1.0f + fex2(-1.4426950408889634f * x)); }
__device__ __forceinline__ float tanhf_(float x) { return 1.0f - 2.0f * frcp(1.0f + fex2(2.8853900817779268f * x)); }
__device__ __forceinline__ float fexp(float x) { return fex2(1.4426950408889634f * x); }

// LDS-only barrier: global prefetch stays in flight
__device__ __forceinline__ void bar() {
    asm volatile("s_waitcnt lgkmcnt(0)" ::: "memory");
    __builtin_amdgcn_s_barrier();
    asm volatile("" ::: "memory");
}

#define MFMA(A, B, C) __builtin_amdgcn_mfma_f32_16x16x32_bf16((A), (B), (C), 0, 0, 0)

__global__ __launch_bounds__(NTHREADS, 2) void gru_persist(
    const float* __restrict__ x, const float* __restrict__ wih, const float* __restrict__ whh,
    const float* __restrict__ bih, const float* __restrict__ bhh,
    const float* __restrict__ h2ow, const float* __restrict__ h2ob_p,
    const float* __restrict__ w1w, const float* __restrict__ w1b_p,
    const float* __restrict__ w2w, const float* __restrict__ w2b_p,
    float* __restrict__ out)
{
    extern __shared__ char smem_raw[];
    Smem& S = *reinterpret_cast<Smem*>(smem_raw);
    const int tid = threadIdx.x;
    const int l = tid & 63;
    const int w = tid >> 6;
    const int g = l >> 4;
    const int cl = l & 15;
    const int b0 = blockIdx.x * RW;

    // ---- prologue: zero LDS ----
    for (int i = tid; i < (int)(sizeof(Smem) / 4); i += NTHREADS) ((u32*)&S)[i] = 0u;
    bar();
    // pack weight fragments into LDS staging
    for (int idx = tid; idx < 384 * NH; idx += NTHREADS) {          // Whh [384][128]
        int c = idx >> 7, k = idx & 127;
        S.whhf[c >> 4][k >> 5][(c & 15) + ((k >> 3) & 3) * 16][k & 7] = f2bf(whh[idx]);
    }
    for (int idx = tid; idx < 384 * NI; idx += NTHREADS) {          // Wih [384][24]
        int c = idx / NI, k = idx - c * NI;
        int lane = (c & 15) + (k >> 3) * 16;
        S.wihf[(c >> 4) * 384 + lane * 8 + (k & 7)] = f2bf(wih[idx]);
    }
    for (int idx = tid; idx < NI * NH; idx += NTHREADS) {           // W1 [24][128]
        int c = idx >> 7, k = idx & 127;
        S.w1f[c >> 4][k >> 5][(c & 15) + ((k >> 3) & 3) * 16][k & 7] = f2bf(w1w[idx]);
    }
    for (int idx = tid; idx < NI * NI; idx += NTHREADS) {           // W2 [24][24]
        int c = idx / NI, k = idx - c * NI;
        S.w2f[c >> 4][(c & 15) + (k >> 3) * 16][k & 7] = f2bf(w2w[idx]);
    }
    for (int k = tid; k < NH; k += NTHREADS)                        // h2o col 0
        S.h2of[k >> 5][((k >> 3) & 3) * 16][k & 7] = f2bf(h2ow[k]);
    // x(t=0) staging
    if (tid < 192) {
        const float* src = x + ((size_t)(b0 + tid / 12) * TSTEPS) * 48 + (tid % 12) * 4;
        *(float4*)&S.xt[0][tid / 12][(tid % 12) * 4] = *(const float4*)src;
    }
    bar();

    // ---- weights -> persistent registers (per-wave gate tiles w, w+8, w+16) ----
    bf16x8 wihR[3], whhR[3][4], w1R[4], w2R[2], h2oR[4];
#pragma unroll
    for (int s = 0; s < 3; ++s) {
        int tw = w + 8 * s;
        wihR[s] = *(const bf16x8*)&S.wihf[tw * 384 + l * 8];
#pragma unroll
        for (int kt = 0; kt < 4; ++kt) whhR[s][kt] = *(const bf16x8*)&S.whhf[tw][kt][l][0];
    }
#pragma unroll
    for (int kt = 0; kt < 4; ++kt) {
        w1R[kt] = *(const bf16x8*)&S.w1f[w & 1][kt][l][0];
        h2oR[kt] = *(const bf16x8*)&S.h2of[kt][l][0];
    }
    w2R[0] = *(const bf16x8*)&S.w2f[0][l][0];
    w2R[1] = *(const bf16x8*)&S.w2f[1][l][0];

    // per-lane constants
    const float bR  = bih[w * 16 + cl] + bhh[w * 16 + cl];
    const float bZ  = bih[128 + w * 16 + cl] + bhh[128 + w * 16 + cl];
    const float bxN = bih[256 + w * 16 + cl];
    const float bhN = bhh[256 + w * 16 + cl];
    const float w1bias = (w == 0) ? w1b_p[cl] : ((w == 1 && cl < 8) ? w1b_p[16 + cl] : 0.0f);
    const float w2b0 = w2b_p[cl];
    const float w2b1 = (cl < 8) ? w2b_p[16 + cl] : 0.0f;
    const float h2ob = h2ob_p[0];

    // h ownership: unit = w*16+cl, rows 4g..4g+3. phi(p) = p + ((p>>3)&1) + 2*(p>>4)
    const int ktH = w >> 1;                         // unit>>5
    const int cc = (2 * w + (cl >> 3)) & 3;         // (unit>>3)&3
    const int hsB0 = 4 * g + 16 * cc + (g >> 1) + 2 * cc;   // phi of slot (4g + 16cc)
    const int eH = cl & 7;
    const int hsl = l + ((l >> 3) & 1) + 2 * (l >> 4);      // phi(l) for reads
    float h_reg[4] = {0.f, 0.f, 0.f, 0.f};

    // build c(0)=h1 and x(0) fragments
    if (tid < 384) {
        int rr = tid & 15, j = tid >> 4;
        float h1 = S.xt[0][rr][j];
        float h2 = S.xt[0][rr][24 + j];
        int lane = rr + (j >> 3) * 16, el = j & 7;
        u16 hi = f2bf(h1);
        S.chi[lane][el] = hi;  S.clo[lane][el] = f2bf(h1 - bf2f(hi));
        S.x1hi[lane][el] = hi;
        S.x2hi[lane][el] = f2bf(h2);
    }
    // 2-deep x prefetch: xfA holds x(t+1), xfB holds x(t+2)
    float4 xfA, xfB;
    if (tid < 192) {
        const float* src = x + ((size_t)(b0 + tid / 12) * TSTEPS + 1) * 48 + (tid % 12) * 4;
        xfA = *(const float4*)src;
    }
    __syncthreads();

    for (int t = 0; t < TSTEPS; ++t) {
        const int nxt = (t + 1) & 1;
        const bool ld2 = (tid < 192) && (t + 2 < TSTEPS);
        const bool st1 = (tid < 192) && (t + 1 < TSTEPS);
        if (ld2) {
            const float* src = x + ((size_t)(b0 + tid / 12) * TSTEPS + (t + 2)) * 48 + (tid % 12) * 4;
            xfB = *(const float4*)src;
        }
        // ---- phase 1: gate matmuls, split hi/lo chains (<=5 links each) ----
        f32x4 aRh = {bR, bR, bR, bR},    aRl = {0.f, 0.f, 0.f, 0.f};
        f32x4 aZh = {bZ, bZ, bZ, bZ},    aZl = {0.f, 0.f, 0.f, 0.f};
        f32x4 aNx = {bxN, bxN, bxN, bxN};
        f32x4 aHh = {bhN, bhN, bhN, bhN}, aHl = {0.f, 0.f, 0.f, 0.f};
        {
            bf16x8 cH = *(const bf16x8*)&S.chi[l][0];
            bf16x8 cL = *(const bf16x8*)&S.clo[l][0];
            aRh = MFMA(cH, wihR[0], aRh);  aRl = MFMA(cL, wihR[0], aRl);
            aZh = MFMA(cH, wihR[1], aZh);  aZl = MFMA(cL, wihR[1], aZl);
            aNx = MFMA(cH, wihR[2], aNx);  aNx = MFMA(cL, wihR[2], aNx);
#pragma unroll
            for (int kt = 0; kt < 4; ++kt) {
                bf16x8 hH = *(const bf16x8*)&S.hhi[kt][hsl][0];
                bf16x8 hL = *(const bf16x8*)&S.hlo[kt][hsl][0];
                aRh = MFMA(hH, whhR[0][kt], aRh);  aRl = MFMA(hL, whhR[0][kt], aRl);
                aZh = MFMA(hH, whhR[1][kt], aZh);  aZl = MFMA(hL, whhR[1][kt], aZl);
                aHh = MFMA(hH, whhR[2][kt], aHh);  aHl = MFMA(hL, whhR[2][kt], aHl);
            }
        }
        if (w == 4 || w == 5) {     // s1/s2 x-parts, hi-only (head path)
            bf16x8 aH = (w == 4) ? *(const bf16x8*)&S.x1hi[l][0]
                                 : *(const bf16x8*)&S.x2hi[l][0];
            f32x4 a0 = {w2b0, w2b0, w2b0, w2b0};
            f32x4 a1v = {w2b1, w2b1, w2b1, w2b1};
            a0 = MFMA(aH, w2R[0], a0);
            a1v = MFMA(aH, w2R[1], a1v);
            float(*ex)[26] = (w == 4) ? S.exs1 : S.exs2;
#pragma unroll
            for (int i = 0; i < 4; ++i) ex[4 * g + i][cl] = a0[i];
            if (cl < 8) {
#pragma unroll
                for (int i = 0; i < 4; ++i) ex[4 * g + i][16 + cl] = a1v[i];
            }
        }
        // gates; h_old in registers
        u16 hnhi[4], hnlo[4];
#pragma unroll
        for (int i = 0; i < 4; ++i) {
            float r = sigm(aRh[i] + aRl[i]);
            float z = sigm(aZh[i] + aZl[i]);
            float n = tanhf_(aNx[i] + r * (aHh[i] + aHl[i]));
            float hv = (1.0f - z) * n + z * h_reg[i];
            h_reg[i] = hv;
            u16 hi = f2bf(hv);
            hnhi[i] = hi;
            hnlo[i] = f2bf(hv - bf2f(hi));
        }
        bar(); // B2: phase-1 frag reads done
        // ---- h store (conflict-free phi slots) + x(t+1) staging ----
#pragma unroll
        for (int i = 0; i < 4; ++i) {
            S.hhi[ktH][hsB0 + i][eH] = hnhi[i];
            S.hlo[ktH][hsB0 + i][eH] = hnlo[i];
        }
        if (st1) *(float4*)&S.xt[nxt][tid / 12][(tid % 12) * 4] = xfA;
        xfA = xfB;
        bar(); // B3: new h + x(t+1) visible
        // ---- phase 2: w1h (w0,w1), out (w2); hi-only reads ----
        if (w < 2) {
            f32x4 acc = {w1bias, w1bias, w1bias, w1bias};
#pragma unroll
            for (int kt = 0; kt < 4; ++kt) {
                bf16x8 hH = *(const bf16x8*)&S.hhi[kt][hsl][0];
                acc = MFMA(hH, w1R[kt], acc);
            }
            int col = w * 16 + cl;
            if (col < 24) {
#pragma unroll
                for (int i = 0; i < 4; ++i) S.exw1h[4 * g + i][col] = acc[i];
            }
        } else if (w == 2) {
            f32x4 acc = {0.f, 0.f, 0.f, 0.f};
#pragma unroll
            for (int kt = 0; kt < 4; ++kt) {
                bf16x8 hH = *(const bf16x8*)&S.hhi[kt][hsl][0];
                acc = MFMA(hH, h2oR[kt], acc);
            }
            if (cl == 0) {
#pragma unroll
                for (int i = 0; i < 4; ++i)
                    out[(size_t)(b0 + 4 * g + i) * TSTEPS + t] = tanhf_(acc[i] + h2ob);
            }
        }
        bar(); // B4: exw1h visible
        // ---- phase 3 (tid>=128): a1,a2 in-register -> c(t+1) + x(t+1) frags ----
        if (tid >= 128) {
            int e = tid - 128;
            int rr = e & 15, j = e >> 4;
            float v = S.exw1h[rr][j];
            float e1 = fexp(tanhf_(v + S.exs1[rr][j]));
            float e2 = fexp(tanhf_(v + S.exs2[rr][j]));
            float inv = frcp(e1 + e2);
            float h1 = S.xt[nxt][rr][j];
            float h2 = S.xt[nxt][rr][24 + j];
            float cv = (e1 * inv) * h1 + (e2 * inv) * h2;
            int lane = rr + (j >> 3) * 16, el = j & 7;
            u16 hi = f2bf(cv);
            S.chi[lane][el] = hi;
            S.clo[lane][el] = f2bf(cv - bf2f(hi));
            S.x1hi[lane][el] = f2bf(h1);
            S.x2hi[lane][el] = f2bf(h2);
        }
        bar(); // B5: c/x frags ready for next step
    }
}

extern "C" void kernel_launch(void* const* d_in, const int* in_sizes, int n_in,
                              void* d_out, int out_size, void* d_ws, size_t ws_size,
                              hipStream_t stream) {
    const float* x    = (const float*)d_in[0];
    const float* wih  = (const float*)d_in[1];
    const float* whh  = (const float*)d_in[2];
    const float* bih  = (const float*)d_in[3];
    const float* bhh  = (const float*)d_in[4];
    const float* h2ow = (const float*)d_in[5];
    const float* h2ob = (const float*)d_in[6];
    const float* w1w  = (const float*)d_in[7];
    const float* w1b  = (const float*)d_in[8];
    const float* w2w  = (const float*)d_in[9];
    const float* w2b  = (const float*)d_in[10];
    float* out = (float*)d_out;

    const size_t smem = sizeof(Smem);
    hipFuncSetAttribute((const void*)gru_persist,
                        hipFuncAttributeMaxDynamicSharedMemorySize, (int)smem);
    gru_persist<<<NWG, NTHREADS, smem, stream>>>(x, wih, whh, bih, bhh,
                                                 h2ow, h2ob, w1w, w1b, w2w, w2b, out);
}

// Round 5
// 536.432 us; speedup vs baseline: 1.2550x; 1.0009x over previous
//
#include <hip/hip_runtime.h>

#define TSTEPS 336
#define NI 24
#define NH 128
#define RW 16          // batch rows per workgroup
#define NTHREADS 512
#define NWG 256        // 4096 / RW

typedef __attribute__((ext_vector_type(8))) short bf16x8;
typedef __attribute__((ext_vector_type(4))) float f32x4;
typedef unsigned short u16;
typedef unsigned int u32;

// Weight staging: used only in the prologue, then re-used (union) for loop-live data.
struct __align__(16) Stage {
    u16 whhf[24][4][64][8];           // 98304 B
    u16 wihf[24 * 384 + 128];         // 18688 B
    u16 w1f[2][4][64][8];             // 8192
    u16 w2f[2][64][8];                // 2048
    u16 h2of[4][64][8];               // 4096
};                                    // 131328 B
struct __align__(16) Live {
    u16 hhi[2][4][72][8];             // 9216  h hi frags, double-buffered, phi-swizzled slots
    u16 hlo[2][4][72][8];             // 9216
    u16 chi[64][8], clo[64][8];       // 2048  c hi/lo A-frags (lanes>=48 zero)
    u16 x1hi[64][8], x2hi[64][8];     // 2048  x A-frags (hi only, head path)
    float exw1h[16][28], exs1[16][28], exs2[16][28]; // 5376, stride-28 (2-way banks)
};                                    // 27904 B
struct __align__(16) Smem {
    union { Stage st; Live lv; } u;
    float xt[2][16][52];              // 6656  x staging (outside union: live during prologue)
};                                    // 137984 B
static_assert(sizeof(Smem) <= 163840, "LDS overflow");

__device__ __forceinline__ u16 f2bf(float f) {
    u32 u = __float_as_uint(f);
    return (u16)((u + 0x7FFFu + ((u >> 16) & 1u)) >> 16);
}
__device__ __forceinline__ float bf2f(u16 h) { return __uint_as_float(((u32)h) << 16); }
__device__ __forceinline__ float frcp(float x) { return __builtin_amdgcn_rcpf(x); }
__device__ __forceinline__ float fex2(float x) { return __builtin_amdgcn_exp2f(x); }
__device__ __forceinline__ float sigm(float x) { return frcp(1.0f + fex2(-1.4426950408889634f * x)); }
__device__ __forceinline__ float tanhf_(float x) { return 1.0f - 2.0f * frcp(1.0f + fex2(2.8853900817779268f * x)); }
__device__ __forceinline__ float fexp(float x) { return fex2(1.4426950408889634f * x); }

// LDS-only barrier: global prefetch stays in flight
__device__ __forceinline__ void bar() {
    asm volatile("s_waitcnt lgkmcnt(0)" ::: "memory");
    __builtin_amdgcn_s_barrier();
    asm volatile("" ::: "memory");
}

#define MFMA(A, B, C) __builtin_amdgcn_mfma_f32_16x16x32_bf16((A), (B), (C), 0, 0, 0)

__global__ __launch_bounds__(NTHREADS, 2) void gru_persist(
    const float* __restrict__ x, const float* __restrict__ wih, const float* __restrict__ whh,
    const float* __restrict__ bih, const float* __restrict__ bhh,
    const float* __restrict__ h2ow, const float* __restrict__ h2ob_p,
    const float* __restrict__ w1w, const float* __restrict__ w1b_p,
    const float* __restrict__ w2w, const float* __restrict__ w2b_p,
    float* __restrict__ out)
{
    extern __shared__ char smem_raw[];
    Smem& S = *reinterpret_cast<Smem*>(smem_raw);
    Stage& ST = S.u.st;
    Live& LV = S.u.lv;
    const int tid = threadIdx.x;
    const int l = tid & 63;
    const int w = tid >> 6;
    const int g = l >> 4;
    const int cl = l & 15;
    const int b0 = blockIdx.x * RW;

    // ---- prologue: zero staging region, pack weight fragments ----
    for (int i = tid; i < (int)(sizeof(Stage) / 4); i += NTHREADS) ((u32*)&ST)[i] = 0u;
    bar();
    for (int idx = tid; idx < 384 * NH; idx += NTHREADS) {          // Whh [384][128]
        int c = idx >> 7, k = idx & 127;
        ST.whhf[c >> 4][k >> 5][(c & 15) + ((k >> 3) & 3) * 16][k & 7] = f2bf(whh[idx]);
    }
    for (int idx = tid; idx < 384 * NI; idx += NTHREADS) {          // Wih [384][24]
        int c = idx / NI, k = idx - c * NI;
        int lane = (c & 15) + (k >> 3) * 16;
        ST.wihf[(c >> 4) * 384 + lane * 8 + (k & 7)] = f2bf(wih[idx]);
    }
    for (int idx = tid; idx < NI * NH; idx += NTHREADS) {           // W1 [24][128]
        int c = idx >> 7, k = idx & 127;
        ST.w1f[c >> 4][k >> 5][(c & 15) + ((k >> 3) & 3) * 16][k & 7] = f2bf(w1w[idx]);
    }
    for (int idx = tid; idx < NI * NI; idx += NTHREADS) {           // W2 [24][24]
        int c = idx / NI, k = idx - c * NI;
        ST.w2f[c >> 4][(c & 15) + (k >> 3) * 16][k & 7] = f2bf(w2w[idx]);
    }
    for (int k = tid; k < NH; k += NTHREADS)                        // h2o col 0
        ST.h2of[k >> 5][((k >> 3) & 3) * 16][k & 7] = f2bf(h2ow[k]);
    if (tid < 192) {                                                // x(t=0)
        const float* src = x + ((size_t)(b0 + tid / 12) * TSTEPS) * 48 + (tid % 12) * 4;
        *(float4*)&S.xt[0][tid / 12][(tid % 12) * 4] = *(const float4*)src;
    }
    bar();

    // ---- weights -> persistent registers ----
    bf16x8 wihR[3], whhR[3][4], headR[4];
#pragma unroll
    for (int s = 0; s < 3; ++s) {
        int tw = w + 8 * s;
        wihR[s] = *(const bf16x8*)&ST.wihf[tw * 384 + l * 8];
#pragma unroll
        for (int kt = 0; kt < 4; ++kt) whhR[s][kt] = *(const bf16x8*)&ST.whhf[tw][kt][l][0];
    }
    if (w < 2) {
#pragma unroll
        for (int kt = 0; kt < 4; ++kt) headR[kt] = *(const bf16x8*)&ST.w1f[w][kt][l][0];
    } else if (w == 2) {
#pragma unroll
        for (int kt = 0; kt < 4; ++kt) headR[kt] = *(const bf16x8*)&ST.h2of[kt][l][0];
    } else {
        headR[0] = *(const bf16x8*)&ST.w2f[0][l][0];
        headR[1] = *(const bf16x8*)&ST.w2f[1][l][0];
        headR[2] = headR[0];
        headR[3] = headR[1];
    }
    bar();   // everyone done reading staging before overwrite

    // ---- re-zero live region (aliases staging) ----
    for (int i = tid; i < (int)(sizeof(Live) / 4); i += NTHREADS) ((u32*)&LV)[i] = 0u;

    // per-lane constants
    const float bR  = bih[w * 16 + cl] + bhh[w * 16 + cl];
    const float bZ  = bih[128 + w * 16 + cl] + bhh[128 + w * 16 + cl];
    const float bxN = bih[256 + w * 16 + cl];
    const float bhN = bhh[256 + w * 16 + cl];
    const float w1bias = (w == 0) ? w1b_p[cl] : ((w == 1 && cl < 8) ? w1b_p[16 + cl] : 0.0f);
    const float w2b0 = w2b_p[cl];
    const float w2b1 = (cl < 8) ? w2b_p[16 + cl] : 0.0f;
    const float h2ob = h2ob_p[0];

    // h ownership + phi-swizzle (phi(p) = p + ((p>>3)&1) + 2*(p>>4))
    const int ktH = w >> 1;
    const int cc = (2 * w + (cl >> 3)) & 3;
    const int hsB0 = 4 * g + 16 * cc + (g >> 1) + 2 * cc;
    const int eH = cl & 7;
    const int hsl = l + ((l >> 3) & 1) + 2 * (l >> 4);
    float h_reg[4] = {0.f, 0.f, 0.f, 0.f};
    bar();   // live region zeroed

    // build c(0)=h1(0) and x(0) fragments
    if (tid < 384) {
        int rr = tid & 15, j = tid >> 4;
        float h1 = S.xt[0][rr][j];
        float h2 = S.xt[0][rr][24 + j];
        int lane = rr + (j >> 3) * 16, el = j & 7;
        u16 hi = f2bf(h1);
        LV.chi[lane][el] = hi;  LV.clo[lane][el] = f2bf(h1 - bf2f(hi));
        LV.x1hi[lane][el] = hi;
        LV.x2hi[lane][el] = f2bf(h2);
    }
    float4 xfA, xfB;
    if (tid < 192) {
        const float* src = x + ((size_t)(b0 + tid / 12) * TSTEPS + 1) * 48 + (tid % 12) * 4;
        xfA = *(const float4*)src;
    }
    // gh(0) carry: h(-1)=0 -> biases only
    f32x4 gR = {bR, bR, bR, bR};
    f32x4 gZ = {bZ, bZ, bZ, bZ};
    f32x4 gN = {bhN, bhN, bhN, bhN};
    __syncthreads();

    for (int t = 0; t < TSTEPS; ++t) {
        const int cb = t & 1;          // h buffer for h(t)
        const int nxt = (t + 1) & 1;   // xt buffer holding x(t+1)
        const bool ld2 = (tid < 192) && (t + 2 < TSTEPS);
        const bool st1 = (tid < 192) && (t + 1 < TSTEPS);
        if (ld2) {
            const float* src = x + ((size_t)(b0 + tid / 12) * TSTEPS + (t + 2)) * 48 + (tid % 12) * 4;
            xfB = *(const float4*)src;
        }
        // ---- P1: finish gates with c(t); gR/gZ/gN carry h-part from prev tail ----
        f32x4 aN = {bxN, bxN, bxN, bxN};
        {
            bf16x8 cH = *(const bf16x8*)&LV.chi[l][0];
            bf16x8 cL = *(const bf16x8*)&LV.clo[l][0];
            gR = MFMA(cH, wihR[0], gR);  gR = MFMA(cL, wihR[0], gR);
            gZ = MFMA(cH, wihR[1], gZ);  gZ = MFMA(cL, wihR[1], gZ);
            aN = MFMA(cH, wihR[2], aN);  aN = MFMA(cL, wihR[2], aN);
        }
        if (w == 4 || w == 5) {     // s1/s2 x-parts (x(t) frags, hi-only)
            bf16x8 aH = (w == 4) ? *(const bf16x8*)&LV.x1hi[l][0]
                                 : *(const bf16x8*)&LV.x2hi[l][0];
            f32x4 a0 = {w2b0, w2b0, w2b0, w2b0};
            f32x4 a1v = {w2b1, w2b1, w2b1, w2b1};
            a0 = MFMA(aH, headR[0], a0);
            a1v = MFMA(aH, headR[1], a1v);
            float(*ex)[28] = (w == 4) ? LV.exs1 : LV.exs2;
#pragma unroll
            for (int i = 0; i < 4; ++i) ex[4 * g + i][cl] = a0[i];
            if (cl < 8) {
#pragma unroll
                for (int i = 0; i < 4; ++i) ex[4 * g + i][16 + cl] = a1v[i];
            }
        }
        // gates; h_old in registers; store h(t) to buffer cb (no barrier needed before)
#pragma unroll
        for (int i = 0; i < 4; ++i) {
            float r = sigm(gR[i]);
            float z = sigm(gZ[i]);
            float n = tanhf_(aN[i] + r * gN[i]);
            float hv = (1.0f - z) * n + z * h_reg[i];
            h_reg[i] = hv;
            u16 hi = f2bf(hv);
            LV.hhi[cb][ktH][hsB0 + i][eH] = hi;
            LV.hlo[cb][ktH][hsB0 + i][eH] = f2bf(hv - bf2f(hi));
        }
        if (st1) *(float4*)&S.xt[nxt][tid / 12][(tid % 12) * 4] = xfA;
        xfA = xfB;
        bar(); // B3: h(t) + x(t+1) + exs visible
        // ---- tail: gh(t+1) on all waves; heads ride the same h-hi registers ----
        gR = (f32x4){bR, bR, bR, bR};
        gZ = (f32x4){bZ, bZ, bZ, bZ};
        gN = (f32x4){bhN, bhN, bhN, bhN};
        f32x4 hacc = (w < 2) ? (f32x4){w1bias, w1bias, w1bias, w1bias}
                             : (f32x4){0.f, 0.f, 0.f, 0.f};
#pragma unroll
        for (int kt = 0; kt < 4; ++kt) {
            bf16x8 hH = *(const bf16x8*)&LV.hhi[cb][kt][hsl][0];
            bf16x8 hL = *(const bf16x8*)&LV.hlo[cb][kt][hsl][0];
            gR = MFMA(hH, whhR[0][kt], gR);  gR = MFMA(hL, whhR[0][kt], gR);
            gZ = MFMA(hH, whhR[1][kt], gZ);  gZ = MFMA(hL, whhR[1][kt], gZ);
            gN = MFMA(hH, whhR[2][kt], gN);  gN = MFMA(hL, whhR[2][kt], gN);
            if (w < 3) hacc = MFMA(hH, headR[kt], hacc);
        }
        if (w < 2) {
            int col = w * 16 + cl;
            if (col < 24) {
#pragma unroll
                for (int i = 0; i < 4; ++i) LV.exw1h[4 * g + i][col] = hacc[i];
            }
        } else if (w == 2) {
            if (cl == 0) {
#pragma unroll
                for (int i = 0; i < 4; ++i)
                    out[(size_t)(b0 + 4 * g + i) * TSTEPS + t] = tanhf_(hacc[i] + h2ob);
            }
        }
        bar(); // B4: exw1h visible
        // ---- phase 3 (waves 5,6,7; 192 thr x 2 j's): a(t+1) -> c(t+1), x(t+1) frags ----
        if (tid >= 320) {
            int e2 = tid - 320;
            int rr = e2 & 15, m = e2 >> 4;       // m = 0..11
            int j0 = 2 * m;
            float v0 = LV.exw1h[rr][j0],  v1 = LV.exw1h[rr][j0 + 1];
            float p0 = LV.exs1[rr][j0],   p1 = LV.exs1[rr][j0 + 1];
            float q0 = LV.exs2[rr][j0],   q1 = LV.exs2[rr][j0 + 1];
            float h10 = S.xt[nxt][rr][j0],      h11 = S.xt[nxt][rr][j0 + 1];
            float h20 = S.xt[nxt][rr][24 + j0], h21 = S.xt[nxt][rr][24 + j0 + 1];
            float e10 = fexp(tanhf_(v0 + p0)), e20 = fexp(tanhf_(v0 + q0));
            float e11 = fexp(tanhf_(v1 + p1)), e21 = fexp(tanhf_(v1 + q1));
            float i0 = frcp(e10 + e20), i1 = frcp(e11 + e21);
            float cv0 = (e10 * i0) * h10 + (e20 * i0) * h20;
            float cv1 = (e11 * i1) * h11 + (e21 * i1) * h21;
            int lane = rr + (j0 >> 3) * 16, el = j0 & 7;   // el even -> b32-aligned pairs
            u16 c0 = f2bf(cv0), c1 = f2bf(cv1);
            *(u32*)&LV.chi[lane][el] = (u32)c0 | ((u32)c1 << 16);
            *(u32*)&LV.clo[lane][el] = (u32)f2bf(cv0 - bf2f(c0)) | ((u32)f2bf(cv1 - bf2f(c1)) << 16);
            *(u32*)&LV.x1hi[lane][el] = (u32)f2bf(h10) | ((u32)f2bf(h11) << 16);
            *(u32*)&LV.x2hi[lane][el] = (u32)f2bf(h20) | ((u32)f2bf(h21) << 16);
        }
        bar(); // B5: c/x frags ready for next P1
    }
}

extern "C" void kernel_launch(void* const* d_in, const int* in_sizes, int n_in,
                              void* d_out, int out_size, void* d_ws, size_t ws_size,
                              hipStream_t stream) {
    const float* x    = (const float*)d_in[0];
    const float* wih  = (const float*)d_in[1];
    const float* whh  = (const float*)d_in[2];
    const float* bih  = (const float*)d_in[3];
    const float* bhh  = (const float*)d_in[4];
    const float* h2ow = (const float*)d_in[5];
    const float* h2ob = (const float*)d_in[6];
    const float* w1w  = (const float*)d_in[7];
    const float* w1b  = (const float*)d_in[8];
    const float* w2w  = (const float*)d_in[9];
    const float* w2b  = (const float*)d_in[10];
    float* out = (float*)d_out;

    const size_t smem = sizeof(Smem);
    hipFuncSetAttribute((const void*)gru_persist,
                        hipFuncAttributeMaxDynamicSharedMemorySize, (int)smem);
    gru_persist<<<NWG, NTHREADS, smem, stream>>>(x, wih, whh, bih, bhh,
                                                 h2ow, h2ob, w1w, w1b, w2w, w2b, out);
}

// Round 6
// 421.937 us; speedup vs baseline: 1.5956x; 1.2714x over previous
//
#include <hip/hip_runtime.h>

#define TSTEPS 336
#define NI 24
#define NH 128
#define RW 16          // batch rows per workgroup
#define NTHREADS 512
#define NWG 256        // 4096 / RW

typedef __attribute__((ext_vector_type(8))) short bf16x8;
typedef __attribute__((ext_vector_type(4))) float f32x4;
typedef unsigned short u16;
typedef unsigned int u32;

// Weight staging: used only in the prologue, then re-used (union) for loop-live data.
struct __align__(16) Stage {
    u16 whhf[24][4][64][8];           // 98304 B
    u16 wihf[24 * 384 + 128];         // 18688 B
    u16 w1f[2][4][64][8];             // 8192
    u16 w2f[2][64][8];                // 2048
    u16 h2of[4][64][8];               // 4096
};                                    // 131328 B
struct __align__(16) Live {
    u16 hhi[2][4][72][8];             // 9216  h frags (hi only), dbuf, phi-swizzled slots
    u16 chi[64][8], clo[64][8];       // 2048  c hi/lo A-frags (lanes>=48 zero)
    u16 x1hi[2][64][8], x2hi[2][64][8]; // 4096  x A-frags (hi only), dbuf
    float exw1h[16][26], exs1[16][26], exs2[16][26]; // 4992, stride-26 (<=2-way banks)
};                                    // 20352 B
struct __align__(16) Smem {
    union { Stage st; Live lv; } u;
    float xt[2][16][52];              // 6656  x staging (outside union: live during prologue)
};
static_assert(sizeof(Smem) <= 163840, "LDS overflow");

__device__ __forceinline__ u16 f2bf(float f) {
    u32 u = __float_as_uint(f);
    return (u16)((u + 0x7FFFu + ((u >> 16) & 1u)) >> 16);
}
__device__ __forceinline__ float bf2f(u16 h) { return __uint_as_float(((u32)h) << 16); }
__device__ __forceinline__ float frcp(float x) { return __builtin_amdgcn_rcpf(x); }
__device__ __forceinline__ float fex2(float x) { return __builtin_amdgcn_exp2f(x); }
__device__ __forceinline__ float sigm(float x) { return frcp(1.0f + fex2(-1.4426950408889634f * x)); }
__device__ __forceinline__ float tanhf_(float x) { return 1.0f - 2.0f * frcp(1.0f + fex2(2.8853900817779268f * x)); }
__device__ __forceinline__ float fexp(float x) { return fex2(1.4426950408889634f * x); }

// LDS-only barrier: global prefetch stays in flight
__device__ __forceinline__ void bar() {
    asm volatile("s_waitcnt lgkmcnt(0)" ::: "memory");
    __builtin_amdgcn_s_barrier();
    asm volatile("" ::: "memory");
}

#define MFMA(A, B, C) __builtin_amdgcn_mfma_f32_16x16x32_bf16((A), (B), (C), 0, 0, 0)

__global__ __launch_bounds__(NTHREADS, 2) void gru_persist(
    const float* __restrict__ x, const float* __restrict__ wih, const float* __restrict__ whh,
    const float* __restrict__ bih, const float* __restrict__ bhh,
    const float* __restrict__ h2ow, const float* __restrict__ h2ob_p,
    const float* __restrict__ w1w, const float* __restrict__ w1b_p,
    const float* __restrict__ w2w, const float* __restrict__ w2b_p,
    float* __restrict__ out)
{
    extern __shared__ char smem_raw[];
    Smem& S = *reinterpret_cast<Smem*>(smem_raw);
    Stage& ST = S.u.st;
    Live& LV = S.u.lv;
    const int tid = threadIdx.x;
    const int l = tid & 63;
    const int w = tid >> 6;
    const int g = l >> 4;
    const int cl = l & 15;
    const int b0 = blockIdx.x * RW;

    // ---- prologue: zero staging region, pack weight fragments ----
    for (int i = tid; i < (int)(sizeof(Stage) / 4); i += NTHREADS) ((u32*)&ST)[i] = 0u;
    bar();
    for (int idx = tid; idx < 384 * NH; idx += NTHREADS) {          // Whh [384][128]
        int c = idx >> 7, k = idx & 127;
        ST.whhf[c >> 4][k >> 5][(c & 15) + ((k >> 3) & 3) * 16][k & 7] = f2bf(whh[idx]);
    }
    for (int idx = tid; idx < 384 * NI; idx += NTHREADS) {          // Wih [384][24]
        int c = idx / NI, k = idx - c * NI;
        int lane = (c & 15) + (k >> 3) * 16;
        ST.wihf[(c >> 4) * 384 + lane * 8 + (k & 7)] = f2bf(wih[idx]);
    }
    for (int idx = tid; idx < NI * NH; idx += NTHREADS) {           // W1 [24][128]
        int c = idx >> 7, k = idx & 127;
        ST.w1f[c >> 4][k >> 5][(c & 15) + ((k >> 3) & 3) * 16][k & 7] = f2bf(w1w[idx]);
    }
    for (int idx = tid; idx < NI * NI; idx += NTHREADS) {           // W2 [24][24]
        int c = idx / NI, k = idx - c * NI;
        ST.w2f[c >> 4][(c & 15) + (k >> 3) * 16][k & 7] = f2bf(w2w[idx]);
    }
    for (int k = tid; k < NH; k += NTHREADS)                        // h2o col 0
        ST.h2of[k >> 5][((k >> 3) & 3) * 16][k & 7] = f2bf(h2ow[k]);
    if (tid < 192) {                                                // x(t=0)
        const float* src = x + ((size_t)(b0 + tid / 12) * TSTEPS) * 48 + (tid % 12) * 4;
        *(float4*)&S.xt[0][tid / 12][(tid % 12) * 4] = *(const float4*)src;
    }
    bar();

    // ---- weights -> persistent registers ----
    bf16x8 wihR[3], whhR[3][4], headR[4];
#pragma unroll
    for (int s = 0; s < 3; ++s) {
        int tw = w + 8 * s;
        wihR[s] = *(const bf16x8*)&ST.wihf[tw * 384 + l * 8];
#pragma unroll
        for (int kt = 0; kt < 4; ++kt) whhR[s][kt] = *(const bf16x8*)&ST.whhf[tw][kt][l][0];
    }
    if (w < 2) {
#pragma unroll
        for (int kt = 0; kt < 4; ++kt) headR[kt] = *(const bf16x8*)&ST.w1f[w][kt][l][0];
    } else if (w == 2) {
#pragma unroll
        for (int kt = 0; kt < 4; ++kt) headR[kt] = *(const bf16x8*)&ST.h2of[kt][l][0];
    } else {
        headR[0] = *(const bf16x8*)&ST.w2f[0][l][0];
        headR[1] = *(const bf16x8*)&ST.w2f[1][l][0];
        headR[2] = headR[0];
        headR[3] = headR[1];
    }
    bar();   // everyone done reading staging before overwrite

    // ---- re-zero live region (aliases staging) ----
    for (int i = tid; i < (int)(sizeof(Live) / 4); i += NTHREADS) ((u32*)&LV)[i] = 0u;

    // per-lane constants
    const float bR  = bih[w * 16 + cl] + bhh[w * 16 + cl];
    const float bZ  = bih[128 + w * 16 + cl] + bhh[128 + w * 16 + cl];
    const float bxN = bih[256 + w * 16 + cl];
    const float bhN = bhh[256 + w * 16 + cl];
    const float w1bias = (w == 0) ? w1b_p[cl] : ((w == 1 && cl < 8) ? w1b_p[16 + cl] : 0.0f);
    const float w2b0 = w2b_p[cl];
    const float w2b1 = (cl < 8) ? w2b_p[16 + cl] : 0.0f;
    const float h2ob = h2ob_p[0];

    // h ownership + phi-swizzle (phi(p) = p + ((p>>3)&1) + 2*(p>>4))
    const int ktH = w >> 1;
    const int cc = (2 * w + (cl >> 3)) & 3;
    const int hsB0 = 4 * g + 16 * cc + (g >> 1) + 2 * cc;
    const int eH = cl & 7;
    const int hsl = l + ((l >> 3) & 1) + 2 * (l >> 4);
    float h_reg[4] = {0.f, 0.f, 0.f, 0.f};
    bar();   // live region zeroed

    // build c(0)=h1(0) and x(0) fragments (buffer 0)
    if (tid < 384) {
        int rr = tid & 15, j = tid >> 4;
        float h1 = S.xt[0][rr][j];
        float h2 = S.xt[0][rr][24 + j];
        int lane = rr + (j >> 3) * 16, el = j & 7;
        u16 hi = f2bf(h1);
        LV.chi[lane][el] = hi;  LV.clo[lane][el] = f2bf(h1 - bf2f(hi));
        LV.x1hi[0][lane][el] = hi;
        LV.x2hi[0][lane][el] = f2bf(h2);
    }
    float4 xfA, xfB;
    if (tid < 192) {
        const float* src = x + ((size_t)(b0 + tid / 12) * TSTEPS + 1) * 48 + (tid % 12) * 4;
        xfA = *(const float4*)src;
    }
    // gh(0) carry: h(-1)=0 -> biases only
    f32x4 gR = {bR, bR, bR, bR};
    f32x4 gZ = {bZ, bZ, bZ, bZ};
    f32x4 gN = {bhN, bhN, bhN, bhN};
    __syncthreads();

    for (int t = 0; t < TSTEPS; ++t) {
        const int cb = t & 1;          // h & x-frag buffer parity for step t
        const int nxt = (t + 1) & 1;
        const bool ld2 = (tid < 192) && (t + 2 < TSTEPS);
        const bool st1 = (tid < 192) && (t + 1 < TSTEPS);
        if (ld2) {
            const float* src = x + ((size_t)(b0 + tid / 12) * TSTEPS + (t + 2)) * 48 + (tid % 12) * 4;
            xfB = *(const float4*)src;
        }
        // ---- P1: finish gates with c(t); gR/gZ/gN carry h-part from prev tail ----
        f32x4 aN = {bxN, bxN, bxN, bxN};
        {
            bf16x8 cH = *(const bf16x8*)&LV.chi[l][0];
            bf16x8 cL = *(const bf16x8*)&LV.clo[l][0];
            gR = MFMA(cH, wihR[0], gR);  gR = MFMA(cL, wihR[0], gR);
            gZ = MFMA(cH, wihR[1], gZ);  gZ = MFMA(cL, wihR[1], gZ);
            aN = MFMA(cH, wihR[2], aN);  aN = MFMA(cL, wihR[2], aN);
        }
        if (w == 4 || w == 5) {     // s1/s2 x-parts from x(t) frags (buffer cb)
            bf16x8 aH = (w == 4) ? *(const bf16x8*)&LV.x1hi[cb][l][0]
                                 : *(const bf16x8*)&LV.x2hi[cb][l][0];
            f32x4 a0 = {w2b0, w2b0, w2b0, w2b0};
            f32x4 a1v = {w2b1, w2b1, w2b1, w2b1};
            a0 = MFMA(aH, headR[0], a0);
            a1v = MFMA(aH, headR[1], a1v);
            float(*ex)[26] = (w == 4) ? LV.exs1 : LV.exs2;
#pragma unroll
            for (int i = 0; i < 4; ++i) ex[4 * g + i][cl] = a0[i];
            if (cl < 8) {
#pragma unroll
                for (int i = 0; i < 4; ++i) ex[4 * g + i][16 + cl] = a1v[i];
            }
        }
        // gates; h_old in registers; store h(t) (hi only) to buffer cb
#pragma unroll
        for (int i = 0; i < 4; ++i) {
            float r = sigm(gR[i]);
            float z = sigm(gZ[i]);
            float n = tanhf_(aN[i] + r * gN[i]);
            float hv = (1.0f - z) * n + z * h_reg[i];
            h_reg[i] = hv;
            LV.hhi[cb][ktH][hsB0 + i][eH] = f2bf(hv);
        }
        // x(t+1): stage to xt + build x-frags (buffer nxt) from registers
        if (st1) {
            *(float4*)&S.xt[nxt][tid / 12][(tid % 12) * 4] = xfA;
            int row = tid / 12, col0 = (tid % 12) * 4;
            int jj0 = (col0 < 24) ? col0 : col0 - 24;
            int lane = row + (jj0 >> 3) * 16, el0 = jj0 & 7;   // el0 in {0,4}
            u16* dst = (col0 < 24) ? &LV.x1hi[nxt][lane][el0] : &LV.x2hi[nxt][lane][el0];
            u32 lo = (u32)f2bf(xfA.x) | ((u32)f2bf(xfA.y) << 16);
            u32 hi = (u32)f2bf(xfA.z) | ((u32)f2bf(xfA.w) << 16);
            *(u32*)dst = lo;
            *(u32*)(dst + 2) = hi;
        }
        xfA = xfB;
        bar(); // B3: h(t), x(t+1) frags, exs visible
        // ---- tail: gh(t+1) on all waves (hi only); heads ride the same registers ----
        gR = (f32x4){bR, bR, bR, bR};
        gZ = (f32x4){bZ, bZ, bZ, bZ};
        gN = (f32x4){bhN, bhN, bhN, bhN};
        f32x4 hacc = (w < 2) ? (f32x4){w1bias, w1bias, w1bias, w1bias}
                             : (f32x4){0.f, 0.f, 0.f, 0.f};
#pragma unroll
        for (int kt = 0; kt < 4; ++kt) {
            bf16x8 hH = *(const bf16x8*)&LV.hhi[cb][kt][hsl][0];
            gR = MFMA(hH, whhR[0][kt], gR);
            gZ = MFMA(hH, whhR[1][kt], gZ);
            gN = MFMA(hH, whhR[2][kt], gN);
            if (w < 3) hacc = MFMA(hH, headR[kt], hacc);
        }
        if (w < 2) {
            int col = w * 16 + cl;
            if (col < 24) {
#pragma unroll
                for (int i = 0; i < 4; ++i) LV.exw1h[4 * g + i][col] = hacc[i];
            }
        } else if (w == 2) {
            if (cl == 0) {
#pragma unroll
                for (int i = 0; i < 4; ++i)
                    out[(size_t)(b0 + 4 * g + i) * TSTEPS + t] = tanhf_(hacc[i] + h2ob);
            }
        }
        bar(); // B4: exw1h visible
        // ---- phase 3 (384 thr x 1): a(t+1) -> c(t+1) frags ----
        if (tid < 384) {
            int rr = tid & 15, j = tid >> 4;
            float v = LV.exw1h[rr][j];
            float e1 = fexp(tanhf_(v + LV.exs1[rr][j]));
            float e2 = fexp(tanhf_(v + LV.exs2[rr][j]));
            float inv = frcp(e1 + e2);
            float h1 = S.xt[nxt][rr][j];
            float h2 = S.xt[nxt][rr][24 + j];
            float cv = (e1 * inv) * h1 + (e2 * inv) * h2;
            int lane = rr + (j >> 3) * 16, el = j & 7;
            u16 hi = f2bf(cv);
            LV.chi[lane][el] = hi;
            LV.clo[lane][el] = f2bf(cv - bf2f(hi));
        }
        bar(); // B5: c frags ready for next P1
    }
}

extern "C" void kernel_launch(void* const* d_in, const int* in_sizes, int n_in,
                              void* d_out, int out_size, void* d_ws, size_t ws_size,
                              hipStream_t stream) {
    const float* x    = (const float*)d_in[0];
    const float* wih  = (const float*)d_in[1];
    const float* whh  = (const float*)d_in[2];
    const float* bih  = (const float*)d_in[3];
    const float* bhh  = (const float*)d_in[4];
    const float* h2ow = (const float*)d_in[5];
    const float* h2ob = (const float*)d_in[6];
    const float* w1w  = (const float*)d_in[7];
    const float* w1b  = (const float*)d_in[8];
    const float* w2w  = (const float*)d_in[9];
    const float* w2b  = (const float*)d_in[10];
    float* out = (float*)d_out;

    const size_t smem = sizeof(Smem);
    hipFuncSetAttribute((const void*)gru_persist,
                        hipFuncAttributeMaxDynamicSharedMemorySize, (int)smem);
    gru_persist<<<NWG, NTHREADS, smem, stream>>>(x, wih, whh, bih, bhh,
                                                 h2ow, h2ob, w1w, w1b, w2w, w2b, out);
}